// Round 2
// baseline (2055.655 us; speedup 1.0000x reference)
//
#include <hip/hip_runtime.h>

// ---- problem constants ----
constexpr int B   = 8;
constexpr int N0  = 50000;
constexpr int N1  = 12500;
constexpr int E   = 400000;
constexpr int FIN = 3;
constexpr int C   = 32;
constexpr int Z   = 128;
constexpr int M   = N1 * C;        // 400000
constexpr int DOWN_NNZ = N1 * 4;
constexpr int UP_NNZ   = N0 * 3;
constexpr size_t BN4 = (size_t)B * N0 * 4;   // padded 3-ch buffer stride (floats)

// ---------------- CSR build (over dst) ----------------
__global__ void k_hist(const int* __restrict__ dst, int* __restrict__ cnt) {
    int e = blockIdx.x * 256 + threadIdx.x;
    if (e < E) atomicAdd(&cnt[dst[e]], 1);
}

__global__ void k_scan_chunk(const int* __restrict__ cnt, int* __restrict__ rp,
                             int* __restrict__ part) {
    __shared__ int s[512];
    int t = threadIdx.x;
    int i = blockIdx.x * 512 + t;
    int v = (i < N0) ? cnt[i] : 0;
    s[t] = v;
    __syncthreads();
    for (int off = 1; off < 512; off <<= 1) {
        int add = (t >= off) ? s[t - off] : 0;
        __syncthreads();
        s[t] += add;
        __syncthreads();
    }
    if (i < N0) rp[i] = s[t] - v;
    if (t == 511) part[blockIdx.x] = s[511];
}

__global__ void k_scan_part(int* part, int nb) {
    if (threadIdx.x == 0 && blockIdx.x == 0) {
        int run = 0;
        for (int c = 0; c < nb; c++) { int t = part[c]; part[c] = run; run += t; }
    }
}

__global__ void k_scan_add(const int* __restrict__ part, int* __restrict__ rp,
                           int* __restrict__ pos) {
    int i = blockIdx.x * 256 + threadIdx.x;
    if (i < N0) {
        int r = rp[i] + part[i >> 9];
        rp[i] = r; pos[i] = r;
        if (i == 0) rp[N0] = E;
    }
}

__global__ void k_scatter(const int* __restrict__ ei, const float* __restrict__ norm,
                          int* __restrict__ pos, int* __restrict__ col_s,
                          float* __restrict__ val_s) {
    int e = blockIdx.x * 256 + threadIdx.x;
    if (e < E) {
        int d = ei[E + e];
        int j = atomicAdd(&pos[d], 1);
        col_s[j] = ei[e];
        val_s[j] = norm[e];
    }
}

// ---------------- generic 3-channel propagate (XCD-pinned: b = blockIdx.x & 7) ----------------
// out = [g] + (SCALE2?2:1)*prop(src) - [sub];  strides: SSTR/USTR/OSTR in {3,4}
// grid: 1-D, 196*8 blocks; XCD(id) = id % 8 == b  -> per-XCD gather slice fits L2
template <int SSTR, int USTR, int OSTR, bool HAS_G, bool HAS_SUB, bool SCALE2>
__global__ void k_prop3g(const int* __restrict__ rp, const int* __restrict__ col,
                         const float* __restrict__ val, const float* __restrict__ src,
                         const float* __restrict__ g, const float* __restrict__ sub,
                         float* __restrict__ out) {
    int bid = blockIdx.x;
    int b = bid & 7;
    int n = (bid >> 3) * 256 + threadIdx.x;
    if (n >= N0) return;
    const float* sb = src + (size_t)b * N0 * SSTR;
    int s = rp[n], e = rp[n + 1];
    float a0 = 0.f, a1 = 0.f, a2 = 0.f;
    for (int j = s; j < e; j++) {
        int sc = col[j]; float w = val[j];
        if (SSTR == 4) {
            float4 v = *(const float4*)(sb + (size_t)sc * 4);
            a0 += w * v.x; a1 += w * v.y; a2 += w * v.z;
        } else {
            const float* p = sb + (size_t)sc * 3;
            a0 += w * p[0]; a1 += w * p[1]; a2 += w * p[2];
        }
    }
    if (SCALE2) { a0 *= 2.f; a1 *= 2.f; a2 *= 2.f; }
    if (HAS_G) {
        const float* gp = g + ((size_t)b * N0 + n) * 4;
        a0 += gp[0]; a1 += gp[1]; a2 += gp[2];
    }
    if (HAS_SUB) {
        const float* up = sub + ((size_t)b * N0 + n) * USTR;
        a0 -= up[0]; a1 -= up[1]; a2 -= up[2];
    }
    if (OSTR == 4) {
        *(float4*)(out + ((size_t)b * N0 + n) * 4) = make_float4(a0, a1, a2, 0.f);
    } else {
        float* op = out + ((size_t)b * N0 + n) * 3;
        op[0] = a0; op[1] = a1; op[2] = a2;
    }
}

// encoder combine: h = relu(b + sum_k T_k @ W_k); x stride 3, T stride 4
__global__ void k_enc_combine(const float* __restrict__ x,
                              const float* __restrict__ T1, const float* __restrict__ T2,
                              const float* __restrict__ T3, const float* __restrict__ T4,
                              const float* __restrict__ T5,
                              const float* __restrict__ W, const float* __restrict__ bias,
                              float* __restrict__ out) {
    int o = threadIdx.x & 31, nl = threadIdx.x >> 5;
    int n = blockIdx.x * 8 + nl;
    int b = blockIdx.y;
    size_t b3 = ((size_t)b * N0 + n) * 3;
    size_t b4 = ((size_t)b * N0 + n) * 4;
    float t[18];
    t[0] = x[b3 + 0]; t[1] = x[b3 + 1]; t[2] = x[b3 + 2];
    const float* Ts[5] = { T1, T2, T3, T4, T5 };
#pragma unroll
    for (int k = 0; k < 5; k++) {
        t[3 + k * 3 + 0] = Ts[k][b4 + 0];
        t[3 + k * 3 + 1] = Ts[k][b4 + 1];
        t[3 + k * 3 + 2] = Ts[k][b4 + 2];
    }
    float acc = bias[o];
#pragma unroll
    for (int q = 0; q < 18; q++) acc += t[q] * W[q * 32 + o];
    out[((size_t)b * N0 + n) * 32 + o] = fmaxf(acc, 0.f);
}

// ---------------- pools (XCD-pinned 1-D grids) ----------------
__global__ void k_pool4(const int* __restrict__ dcol, const float* __restrict__ dval,
                        const float* __restrict__ src, float* __restrict__ out) {
    int bid = blockIdx.x;
    int b = bid & 7;
    int c = threadIdx.x & 31, rl = threadIdx.x >> 5;
    int r = (bid >> 3) * 8 + rl;
    if (r >= N1) return;
    const float* sb = src + (size_t)b * N0 * 32;
    float a = 0.f;
#pragma unroll
    for (int t = 0; t < 4; t++) {
        int idx = 4 * r + t;
        a += dval[idx] * sb[(size_t)dcol[idx] * 32 + c];
    }
    out[((size_t)b * N1 + r) * 32 + c] = a;
}

// up-pool fused with dec0 k=0 conv: hup = P_up @ S1; acc = bias + hup @ W0
__global__ void k_pool3_init(const int* __restrict__ ucol, const float* __restrict__ uval,
                             const float* __restrict__ src, const float* __restrict__ W,
                             const float* __restrict__ bias,
                             float* __restrict__ hup, float* __restrict__ acc) {
    int bid = blockIdx.x;              // grid = 6250*8 exact
    int b = bid & 7;
    int c = threadIdx.x & 31, rl = threadIdx.x >> 5;
    int i = (bid >> 3) * 8 + rl;
    const float* sb = src + (size_t)b * N1 * 32;
    float a = 0.f;
#pragma unroll
    for (int t = 0; t < 3; t++) {
        int idx = 3 * i + t;
        a += uval[idx] * sb[(size_t)ucol[idx] * 32 + c];
    }
    size_t base = ((size_t)b * N0 + i) * 32;
    hup[base + c] = a;
    float Wr[32];
#pragma unroll
    for (int cc = 0; cc < 32; cc++) Wr[cc] = W[cc * 32 + c];
    float o = bias[c];
#pragma unroll
    for (int cc = 0; cc < 32; cc++) o += __shfl(a, cc, 32) * Wr[cc];
    acc[base + c] = o;
}

// ---------------- enc linear: split-K two stage ----------------
__global__ void k_enclin1(const float* __restrict__ S0, const float* __restrict__ W,
                          float* __restrict__ partial) {
    int zl = threadIdx.x & 127, half = threadIdx.x >> 7;
    int m0 = blockIdx.x * 128;
    float acc[B];
#pragma unroll
    for (int b = 0; b < B; b++) acc[b] = 0.f;
    for (int i = 0; i < 64; i++) {
        int m = m0 + half + 2 * i;
        float w = W[(size_t)m * Z + zl];
#pragma unroll
        for (int b = 0; b < B; b++) acc[b] += S0[(size_t)b * M + m] * w;
    }
    __shared__ float red[128 * B];
    if (half == 1) {
#pragma unroll
        for (int b = 0; b < B; b++) red[zl * B + b] = acc[b];
    }
    __syncthreads();
    if (half == 0) {
#pragma unroll
        for (int b = 0; b < B; b++)
            partial[(size_t)blockIdx.x * 1024 + b * 128 + zl] = acc[b] + red[zl * B + b];
    }
}

// stage 2a: tree-reduce partials across k, coalesced along i.
__global__ void k_enclin2a(const float* __restrict__ partial, float* __restrict__ p2) {
    int i  = blockIdx.x * 256 + threadIdx.x;   // 0..1023
    int kc = blockIdx.y;                       // 0..24
    int k0 = kc * 125;
    float a = 0.f;
    for (int k = k0; k < k0 + 125; k++) a += partial[(size_t)k * 1024 + i];
    p2[(size_t)kc * 1024 + i] = a;
}

__global__ void k_enclin2b(const float* __restrict__ p2, const float* __restrict__ bias,
                           float* __restrict__ z) {
    int i = blockIdx.x * 256 + threadIdx.x;
    if (i >= B * Z) return;
    float a = bias[i & 127];
#pragma unroll
    for (int k = 0; k < 25; k++) a += p2[(size_t)k * 1024 + i];
    z[i] = a;
}

__global__ void k_declin(const float* __restrict__ z, const float* __restrict__ W,
                         const float* __restrict__ bias, float* __restrict__ out) {
    __shared__ float zs[B * Z];
    for (int i = threadIdx.x; i < B * Z; i += 256) zs[i] = z[i];
    __syncthreads();
    int m = blockIdx.x * 256 + threadIdx.x;
    if (m >= M) return;
    float bv = bias[m];
    float acc[B];
#pragma unroll
    for (int b = 0; b < B; b++) acc[b] = bv;
    for (int j = 0; j < Z; j++) {
        float w = W[(size_t)j * M + m];
#pragma unroll
        for (int b = 0; b < B; b++) acc[b] += zs[b * Z + j] * w;
    }
#pragma unroll
    for (int b = 0; b < B; b++) out[(size_t)b * M + m] = fmaxf(acc[b], 0.f);
}

// ---------------- dec0: propagate + conv, batch-split & XCD-pinned ----------------
// grid = 50000 (6250 n-blocks x 8 batches); XCD(id) = id%8 == b
template <bool HAS_SUB, bool WRITE_TX>
__global__ void k_prop_fused32(const int* __restrict__ rp, const int* __restrict__ col,
                               const float* __restrict__ val, const float* __restrict__ src,
                               const float* __restrict__ sub, float* __restrict__ txout,
                               const float* __restrict__ W, float* __restrict__ accb) {
    int bid = blockIdx.x;
    int b = bid & 7;
    int lane = threadIdx.x & 31, nl = threadIdx.x >> 5;
    int n = (bid >> 3) * 8 + nl;           // exact
    int s = rp[n], e = rp[n + 1];
    const float* sb = src + (size_t)b * N0 * 32;
    float a = 0.f;
    for (int j = s; j < e; j++) {
        a += val[j] * sb[(size_t)col[j] * 32 + lane];
    }
    float Wr[32];
#pragma unroll
    for (int cc = 0; cc < 32; cc++) Wr[cc] = W[cc * 32 + lane];
    size_t base = ((size_t)b * N0 + n) * 32;
    float t = HAS_SUB ? 2.f * a - sub[base + lane] : a;
    if (WRITE_TX) txout[base + lane] = t;
    float o = 0.f;
#pragma unroll
    for (int cc = 0; cc < 32; cc++) o += __shfl(t, cc, 32) * Wr[cc];
    accb[base + lane] += o;
}

// ---------------- dec1: project h through all six 32->3 W_k ----------------
__global__ void k_proj(const float* __restrict__ ACC, const float* __restrict__ W1,
                       float* __restrict__ G) {
    int lane = threadIdx.x & 31, nl = threadIdx.x >> 5;
    int n = blockIdx.x * 8 + nl;           // grid = N0/8 exactly
    int k = (lane < 18) ? lane / 3 : 0;
    int c = (lane < 18) ? lane % 3 : 0;
    float Wr[32];
#pragma unroll
    for (int cc = 0; cc < 32; cc++) Wr[cc] = W1[k * 96 + cc * 3 + c];
#pragma unroll
    for (int b = 0; b < B; b++) {
        float t = fmaxf(ACC[((size_t)b * N0 + n) * 32 + lane], 0.f);
        float o = 0.f;
#pragma unroll
        for (int cc = 0; cc < 32; cc++) o += __shfl(t, cc, 32) * Wr[cc];
        if (lane < 18) G[(size_t)k * BN4 + ((size_t)b * N0 + n) * 4 + c] = o;
    }
}

// ---------------- launch ----------------
extern "C" void kernel_launch(void* const* d_in, const int* in_sizes, int n_in,
                              void* d_out, int out_size, void* d_ws, size_t ws_size,
                              hipStream_t stream) {
    const float* x        = (const float*)d_in[0];
    const int*   ei       = (const int*)d_in[1];
    const float* A_norm   = (const float*)d_in[2];
    const int*   down_idx = (const int*)d_in[3];
    const float* down_val = (const float*)d_in[4];
    const int*   up_idx   = (const int*)d_in[5];
    const float* up_val   = (const float*)d_in[6];
    const float* W_enc0   = (const float*)d_in[7];
    const float* b_enc0   = (const float*)d_in[8];
    const float* W_dec0   = (const float*)d_in[9];
    const float* b_dec0   = (const float*)d_in[10];
    const float* W_dec1   = (const float*)d_in[11];
    const float* enc_lin_W = (const float*)d_in[12];
    const float* enc_lin_b = (const float*)d_in[13];
    const float* dec_lin_W = (const float*)d_in[14];
    const float* dec_lin_b = (const float*)d_in[15];
    float* OUT = (float*)d_out;

    char* w8 = (char*)d_ws;
    auto alignup = [](size_t v) { return (v + 255) & ~(size_t)255; };
    size_t off = 0;
    auto carve = [&](size_t bytes) { void* p = w8 + off; off = alignup(off + bytes); return p; };

    int*   row_ptr = (int*)carve((size_t)(N0 + 1) * 4);
    int*   poscnt  = (int*)carve((size_t)N0 * 4);
    int*   part    = (int*)carve(128 * 4);
    int*   col_s   = (int*)carve((size_t)E * 4);
    float* val_s   = (float*)carve((size_t)E * 4);
    float* zbuf    = (float*)carve((size_t)B * Z * 4);
    constexpr size_t BIG = (size_t)B * N0 * C;            // 12.8M floats
    float* A1 = (float*)carve(BIG * 4);
    float* A2 = (float*)carve(BIG * 4);
    float* A3 = (float*)carve(BIG * 4);
    (void)ws_size; (void)n_in; (void)in_sizes; (void)out_size;

    // aliases:
    float* T1 = A1 + 0 * BN4;   // padded encoder T buffers (32 MB in A1)
    float* T2 = A1 + 1 * BN4;
    float* T3 = A1 + 2 * BN4;
    float* T4 = A1 + 3 * BN4;
    float* T5 = A1 + 4 * BN4;
    float* HENC = A2;
    float* S0   = A3;
    float* PART = A2;           // enclin partials (12.8 MB), HENC dead by then
    float* P2   = A3 + (size_t)8 * 1024 * 1024;  // 100 KB at +32MB in A3
    float* S1   = A1;           // declin out [B,M]
    float* HUP  = A2;
    float* ACC  = A3;
    float* G    = A1;           // 6 x BN4 (38.4 MB) after dec0
    float* B4   = A2 + 0 * BN4; // Clenshaw b buffers
    float* B3   = A2 + 1 * BN4;
    float* B2   = A2 + 2 * BN4;
    float* B1   = A2 + 3 * BN4;

    const int* dcol = down_idx + DOWN_NNZ;
    const int* ucol = up_idx + UP_NNZ;

    dim3 blk(256);
    dim3 gE((E + 255) / 256);
    dim3 gN0t((N0 + 255) / 256);
    dim3 g3x(((N0 + 255) / 256) * 8);     // 1568, XCD-pinned: b = id & 7
    dim3 gN8(N0 / 8);                     // 6250, exact
    dim3 gNB(N0 / 8, B);
    dim3 gF(N0);                          // 50000: fused32 / pool3_init, b = id & 7
    dim3 gP4(((N1 + 7) / 8) * 8);         // 12504, b = id & 7

    // ---- CSR build over dst ----
    hipMemsetAsync(poscnt, 0, (size_t)N0 * 4, stream);
    k_hist<<<gE, blk, 0, stream>>>(ei + E, poscnt);
    int nchunks = (N0 + 511) / 512;
    k_scan_chunk<<<nchunks, 512, 0, stream>>>(poscnt, row_ptr, part);
    k_scan_part<<<1, 1, 0, stream>>>(part, nchunks);
    k_scan_add<<<gN0t, blk, 0, stream>>>(part, row_ptr, poscnt);
    k_scatter<<<gE, blk, 0, stream>>>(ei, A_norm, poscnt, col_s, val_s);

    // ---- encoder cheb (Cin=3), padded T buffers ----
    k_prop3g<3,3,4,false,false,false><<<g3x, blk, 0, stream>>>(row_ptr, col_s, val_s, x,  nullptr, nullptr, T1);
    k_prop3g<4,3,4,false,true, true ><<<g3x, blk, 0, stream>>>(row_ptr, col_s, val_s, T1, nullptr, x,  T2);
    k_prop3g<4,4,4,false,true, true ><<<g3x, blk, 0, stream>>>(row_ptr, col_s, val_s, T2, nullptr, T1, T3);
    k_prop3g<4,4,4,false,true, true ><<<g3x, blk, 0, stream>>>(row_ptr, col_s, val_s, T3, nullptr, T2, T4);
    k_prop3g<4,4,4,false,true, true ><<<g3x, blk, 0, stream>>>(row_ptr, col_s, val_s, T4, nullptr, T3, T5);
    k_enc_combine<<<gNB, blk, 0, stream>>>(x, T1, T2, T3, T4, T5, W_enc0, b_enc0, HENC);

    // ---- down pool ----
    k_pool4<<<gP4, blk, 0, stream>>>(dcol, down_val, HENC, S0);

    // ---- enc linear (split-K, parallel tree reduce) ----
    k_enclin1<<<3125, blk, 0, stream>>>(S0, enc_lin_W, PART);
    dim3 g2a(4, 25);
    k_enclin2a<<<g2a, blk, 0, stream>>>(PART, P2);
    k_enclin2b<<<4, blk, 0, stream>>>(P2, enc_lin_b, zbuf);

    // ---- dec linear ----
    k_declin<<<(M + 255) / 256, blk, 0, stream>>>(zbuf, dec_lin_W, dec_lin_b, S1);

    // ---- up pool fused with dec0 k=0 conv ----
    k_pool3_init<<<gF, blk, 0, stream>>>(ucol, up_val, S1, W_dec0, b_dec0, HUP, ACC);

    // ---- dec0 cheb (32->32), batch-split, XCD-pinned; rotate A2<->A1, ACC=A3 ----
    k_prop_fused32<false, true ><<<gF, blk, 0, stream>>>(row_ptr, col_s, val_s, A2, nullptr, A1, W_dec0 + 1 * C * C, ACC);
    k_prop_fused32<true,  true ><<<gF, blk, 0, stream>>>(row_ptr, col_s, val_s, A1, A2, A2, W_dec0 + 2 * C * C, ACC);
    k_prop_fused32<true,  true ><<<gF, blk, 0, stream>>>(row_ptr, col_s, val_s, A2, A1, A1, W_dec0 + 3 * C * C, ACC);
    k_prop_fused32<true,  true ><<<gF, blk, 0, stream>>>(row_ptr, col_s, val_s, A1, A2, A2, W_dec0 + 4 * C * C, ACC);
    k_prop_fused32<true,  false><<<gF, blk, 0, stream>>>(row_ptr, col_s, val_s, A2, A1, nullptr, W_dec0 + 5 * C * C, ACC);

    // ---- dec1 via Clenshaw in 3-channel space ----
    k_proj<<<gN8, blk, 0, stream>>>(ACC, W_dec1, G);
    float* G0 = G + 0 * BN4; float* G1 = G + 1 * BN4; float* G2 = G + 2 * BN4;
    float* G3c = G + 3 * BN4; float* G4 = G + 4 * BN4; float* G5 = G + 5 * BN4;
    // b5 = G5; b4 = G4 + 2L b5; b3 = G3 + 2L b4 - b5; b2..; b1..
    k_prop3g<4,4,4,true,false,true ><<<g3x, blk, 0, stream>>>(row_ptr, col_s, val_s, G5, G4, nullptr, B4);
    k_prop3g<4,4,4,true,true, true ><<<g3x, blk, 0, stream>>>(row_ptr, col_s, val_s, B4, G3c, G5, B3);
    k_prop3g<4,4,4,true,true, true ><<<g3x, blk, 0, stream>>>(row_ptr, col_s, val_s, B3, G2, B4, B2);
    k_prop3g<4,4,4,true,true, true ><<<g3x, blk, 0, stream>>>(row_ptr, col_s, val_s, B2, G1, B3, B1);
    // out = G0 + L b1 - b2   (scale 1)
    k_prop3g<4,4,3,true,true, false><<<g3x, blk, 0, stream>>>(row_ptr, col_s, val_s, B1, G0, B2, OUT);
}

// Round 3
// 1654.614 us; speedup vs baseline: 1.2424x; 1.2424x over previous
//
#include <hip/hip_runtime.h>

// ---- problem constants ----
constexpr int B   = 8;
constexpr int N0  = 50000;
constexpr int N1  = 12500;
constexpr int E   = 400000;
constexpr int FIN = 3;
constexpr int C   = 32;
constexpr int Z   = 128;
constexpr int M   = N1 * C;        // 400000
constexpr int DOWN_NNZ = N1 * 4;
constexpr int UP_NNZ   = N0 * 3;
constexpr size_t BN4 = (size_t)B * N0 * 4;   // padded 3-ch buffer stride (floats)

// ---------------- CSR build (over dst) ----------------
__global__ void k_hist(const int* __restrict__ dst, int* __restrict__ cnt) {
    int e = blockIdx.x * 256 + threadIdx.x;
    if (e < E) atomicAdd(&cnt[dst[e]], 1);
}

__global__ void k_scan_chunk(const int* __restrict__ cnt, int* __restrict__ rp,
                             int* __restrict__ part) {
    __shared__ int s[512];
    int t = threadIdx.x;
    int i = blockIdx.x * 512 + t;
    int v = (i < N0) ? cnt[i] : 0;
    s[t] = v;
    __syncthreads();
    for (int off = 1; off < 512; off <<= 1) {
        int add = (t >= off) ? s[t - off] : 0;
        __syncthreads();
        s[t] += add;
        __syncthreads();
    }
    if (i < N0) rp[i] = s[t] - v;
    if (t == 511) part[blockIdx.x] = s[511];
}

__global__ void k_scan_part(int* part, int nb) {
    if (threadIdx.x == 0 && blockIdx.x == 0) {
        int run = 0;
        for (int c = 0; c < nb; c++) { int t = part[c]; part[c] = run; run += t; }
    }
}

__global__ void k_scan_add(const int* __restrict__ part, int* __restrict__ rp,
                           int* __restrict__ pos) {
    int i = blockIdx.x * 256 + threadIdx.x;
    if (i < N0) {
        int r = rp[i] + part[i >> 9];
        rp[i] = r; pos[i] = r;
        if (i == 0) rp[N0] = E;
    }
}

__global__ void k_scatter(const int* __restrict__ ei, const float* __restrict__ norm,
                          int* __restrict__ pos, int* __restrict__ col_s,
                          float* __restrict__ val_s) {
    int e = blockIdx.x * 256 + threadIdx.x;
    if (e < E) {
        int d = ei[E + e];
        int j = atomicAdd(&pos[d], 1);
        col_s[j] = ei[e];
        val_s[j] = norm[e];
    }
}

// ---------------- generic 3-channel propagate (XCD-pinned: b = blockIdx.x & 7) ----------------
// out = [g] + (SCALE2?2:1)*prop(src) - [sub];  strides: SSTR/USTR/OSTR in {3,4}
// 4x unrolled edge loop -> 4 independent gathers in flight (MLP)
template <int SSTR, int USTR, int OSTR, bool HAS_G, bool HAS_SUB, bool SCALE2>
__global__ void k_prop3g(const int* __restrict__ rp, const int* __restrict__ col,
                         const float* __restrict__ val, const float* __restrict__ src,
                         const float* __restrict__ g, const float* __restrict__ sub,
                         float* __restrict__ out) {
    int bid = blockIdx.x;
    int b = bid & 7;
    int n = (bid >> 3) * 256 + threadIdx.x;
    if (n >= N0) return;
    const float* sb = src + (size_t)b * N0 * SSTR;
    int s = rp[n], e = rp[n + 1];
    float a0 = 0.f, a1 = 0.f, a2 = 0.f;
    float b0 = 0.f, b1 = 0.f, b2 = 0.f;
    float c0 = 0.f, c1 = 0.f, c2 = 0.f;
    float d0 = 0.f, d1 = 0.f, d2 = 0.f;
    int j = s;
    for (; j + 4 <= e; j += 4) {
        int sc0 = col[j], sc1 = col[j + 1], sc2 = col[j + 2], sc3 = col[j + 3];
        float w0 = val[j], w1 = val[j + 1], w2 = val[j + 2], w3 = val[j + 3];
        if (SSTR == 4) {
            float4 v0 = *(const float4*)(sb + (size_t)sc0 * 4);
            float4 v1 = *(const float4*)(sb + (size_t)sc1 * 4);
            float4 v2 = *(const float4*)(sb + (size_t)sc2 * 4);
            float4 v3 = *(const float4*)(sb + (size_t)sc3 * 4);
            a0 += w0 * v0.x; a1 += w0 * v0.y; a2 += w0 * v0.z;
            b0 += w1 * v1.x; b1 += w1 * v1.y; b2 += w1 * v1.z;
            c0 += w2 * v2.x; c1 += w2 * v2.y; c2 += w2 * v2.z;
            d0 += w3 * v3.x; d1 += w3 * v3.y; d2 += w3 * v3.z;
        } else {
            const float* p0 = sb + (size_t)sc0 * 3;
            const float* p1 = sb + (size_t)sc1 * 3;
            const float* p2 = sb + (size_t)sc2 * 3;
            const float* p3 = sb + (size_t)sc3 * 3;
            a0 += w0 * p0[0]; a1 += w0 * p0[1]; a2 += w0 * p0[2];
            b0 += w1 * p1[0]; b1 += w1 * p1[1]; b2 += w1 * p1[2];
            c0 += w2 * p2[0]; c1 += w2 * p2[1]; c2 += w2 * p2[2];
            d0 += w3 * p3[0]; d1 += w3 * p3[1]; d2 += w3 * p3[2];
        }
    }
    for (; j < e; j++) {
        int sc = col[j]; float w = val[j];
        if (SSTR == 4) {
            float4 v = *(const float4*)(sb + (size_t)sc * 4);
            a0 += w * v.x; a1 += w * v.y; a2 += w * v.z;
        } else {
            const float* p = sb + (size_t)sc * 3;
            a0 += w * p[0]; a1 += w * p[1]; a2 += w * p[2];
        }
    }
    a0 = (a0 + b0) + (c0 + d0);
    a1 = (a1 + b1) + (c1 + d1);
    a2 = (a2 + b2) + (c2 + d2);
    if (SCALE2) { a0 *= 2.f; a1 *= 2.f; a2 *= 2.f; }
    if (HAS_G) {
        const float* gp = g + ((size_t)b * N0 + n) * 4;
        a0 += gp[0]; a1 += gp[1]; a2 += gp[2];
    }
    if (HAS_SUB) {
        const float* up = sub + ((size_t)b * N0 + n) * USTR;
        a0 -= up[0]; a1 -= up[1]; a2 -= up[2];
    }
    if (OSTR == 4) {
        *(float4*)(out + ((size_t)b * N0 + n) * 4) = make_float4(a0, a1, a2, 0.f);
    } else {
        float* op = out + ((size_t)b * N0 + n) * 3;
        op[0] = a0; op[1] = a1; op[2] = a2;
    }
}

// encoder combine: h = relu(b + sum_k T_k @ W_k); x stride 3, T stride 4
__global__ void k_enc_combine(const float* __restrict__ x,
                              const float* __restrict__ T1, const float* __restrict__ T2,
                              const float* __restrict__ T3, const float* __restrict__ T4,
                              const float* __restrict__ T5,
                              const float* __restrict__ W, const float* __restrict__ bias,
                              float* __restrict__ out) {
    int o = threadIdx.x & 31, nl = threadIdx.x >> 5;
    int n = blockIdx.x * 8 + nl;
    int b = blockIdx.y;
    size_t b3 = ((size_t)b * N0 + n) * 3;
    size_t b4 = ((size_t)b * N0 + n) * 4;
    float t[18];
    t[0] = x[b3 + 0]; t[1] = x[b3 + 1]; t[2] = x[b3 + 2];
    const float* Ts[5] = { T1, T2, T3, T4, T5 };
#pragma unroll
    for (int k = 0; k < 5; k++) {
        t[3 + k * 3 + 0] = Ts[k][b4 + 0];
        t[3 + k * 3 + 1] = Ts[k][b4 + 1];
        t[3 + k * 3 + 2] = Ts[k][b4 + 2];
    }
    float acc = bias[o];
#pragma unroll
    for (int q = 0; q < 18; q++) acc += t[q] * W[q * 32 + o];
    out[((size_t)b * N0 + n) * 32 + o] = fmaxf(acc, 0.f);
}

// ---------------- pools (XCD-pinned 1-D grids) ----------------
__global__ void k_pool4(const int* __restrict__ dcol, const float* __restrict__ dval,
                        const float* __restrict__ src, float* __restrict__ out) {
    int bid = blockIdx.x;
    int b = bid & 7;
    int c = threadIdx.x & 31, rl = threadIdx.x >> 5;
    int r = (bid >> 3) * 8 + rl;
    if (r >= N1) return;
    const float* sb = src + (size_t)b * N0 * 32;
    float a = 0.f;
#pragma unroll
    for (int t = 0; t < 4; t++) {
        int idx = 4 * r + t;
        a += dval[idx] * sb[(size_t)dcol[idx] * 32 + c];
    }
    out[((size_t)b * N1 + r) * 32 + c] = a;
}

// up-pool fused with dec0 k=0 conv: hup = P_up @ S1; acc = bias + hup @ W0
__global__ void k_pool3_init(const int* __restrict__ ucol, const float* __restrict__ uval,
                             const float* __restrict__ src, const float* __restrict__ W,
                             const float* __restrict__ bias,
                             float* __restrict__ hup, float* __restrict__ acc) {
    int bid = blockIdx.x;              // grid = 6250*8 exact
    int b = bid & 7;
    int c = threadIdx.x & 31, rl = threadIdx.x >> 5;
    int i = (bid >> 3) * 8 + rl;
    const float* sb = src + (size_t)b * N1 * 32;
    float a = 0.f;
#pragma unroll
    for (int t = 0; t < 3; t++) {
        int idx = 3 * i + t;
        a += uval[idx] * sb[(size_t)ucol[idx] * 32 + c];
    }
    size_t base = ((size_t)b * N0 + i) * 32;
    hup[base + c] = a;
    float Wr[32];
#pragma unroll
    for (int cc = 0; cc < 32; cc++) Wr[cc] = W[cc * 32 + c];
    float o = bias[c];
#pragma unroll
    for (int cc = 0; cc < 32; cc++) o += __shfl(a, cc, 32) * Wr[cc];
    acc[base + c] = o;
}

// ---------------- enc linear: split-K two stage ----------------
__global__ void k_enclin1(const float* __restrict__ S0, const float* __restrict__ W,
                          float* __restrict__ partial) {
    int zl = threadIdx.x & 127, half = threadIdx.x >> 7;
    int m0 = blockIdx.x * 128;
    float acc[B];
#pragma unroll
    for (int b = 0; b < B; b++) acc[b] = 0.f;
    for (int i = 0; i < 64; i++) {
        int m = m0 + half + 2 * i;
        float w = W[(size_t)m * Z + zl];
#pragma unroll
        for (int b = 0; b < B; b++) acc[b] += S0[(size_t)b * M + m] * w;
    }
    __shared__ float red[128 * B];
    if (half == 1) {
#pragma unroll
        for (int b = 0; b < B; b++) red[zl * B + b] = acc[b];
    }
    __syncthreads();
    if (half == 0) {
#pragma unroll
        for (int b = 0; b < B; b++)
            partial[(size_t)blockIdx.x * 1024 + b * 128 + zl] = acc[b] + red[zl * B + b];
    }
}

// stage 2a: tree-reduce partials across k, coalesced along i.
__global__ void k_enclin2a(const float* __restrict__ partial, float* __restrict__ p2) {
    int i  = blockIdx.x * 256 + threadIdx.x;   // 0..1023
    int kc = blockIdx.y;                       // 0..24
    int k0 = kc * 125;
    float a = 0.f;
    for (int k = k0; k < k0 + 125; k++) a += partial[(size_t)k * 1024 + i];
    p2[(size_t)kc * 1024 + i] = a;
}

__global__ void k_enclin2b(const float* __restrict__ p2, const float* __restrict__ bias,
                           float* __restrict__ z) {
    int i = blockIdx.x * 256 + threadIdx.x;
    if (i >= B * Z) return;
    float a = bias[i & 127];
#pragma unroll
    for (int k = 0; k < 25; k++) a += p2[(size_t)k * 1024 + i];
    z[i] = a;
}

__global__ void k_declin(const float* __restrict__ z, const float* __restrict__ W,
                         const float* __restrict__ bias, float* __restrict__ out) {
    __shared__ float zs[B * Z];
    for (int i = threadIdx.x; i < B * Z; i += 256) zs[i] = z[i];
    __syncthreads();
    int m = blockIdx.x * 256 + threadIdx.x;
    if (m >= M) return;
    float bv = bias[m];
    float acc[B];
#pragma unroll
    for (int b = 0; b < B; b++) acc[b] = bv;
    for (int j = 0; j < Z; j++) {
        float w = W[(size_t)j * M + m];
#pragma unroll
        for (int b = 0; b < B; b++) acc[b] += zs[b * Z + j] * w;
    }
#pragma unroll
    for (int b = 0; b < B; b++) out[(size_t)b * M + m] = fmaxf(acc[b], 0.f);
}

// ---------------- dec0: propagate + conv, batch-split & XCD-pinned, 4x MLP ----------------
// grid = 50000 (6250 n-blocks x 8 batches); XCD(id) = id%8 == b
template <bool HAS_SUB, bool WRITE_TX>
__global__ void k_prop_fused32(const int* __restrict__ rp, const int* __restrict__ col,
                               const float* __restrict__ val, const float* __restrict__ src,
                               const float* __restrict__ sub, float* __restrict__ txout,
                               const float* __restrict__ W, float* __restrict__ accb) {
    int bid = blockIdx.x;
    int b = bid & 7;
    int lane = threadIdx.x & 31, nl = threadIdx.x >> 5;
    int n = (bid >> 3) * 8 + nl;           // exact
    int s = rp[n], e = rp[n + 1];
    const float* sb = src + (size_t)b * N0 * 32;
    float a0 = 0.f, a1 = 0.f, a2 = 0.f, a3 = 0.f;
    int j = s;
    for (; j + 4 <= e; j += 4) {
        int c0 = col[j], c1 = col[j + 1], c2 = col[j + 2], c3 = col[j + 3];
        float w0 = val[j], w1 = val[j + 1], w2 = val[j + 2], w3 = val[j + 3];
        a0 += w0 * sb[(size_t)c0 * 32 + lane];
        a1 += w1 * sb[(size_t)c1 * 32 + lane];
        a2 += w2 * sb[(size_t)c2 * 32 + lane];
        a3 += w3 * sb[(size_t)c3 * 32 + lane];
    }
    for (; j < e; j++) a0 += val[j] * sb[(size_t)col[j] * 32 + lane];
    float a = (a0 + a1) + (a2 + a3);
    float Wr[32];
#pragma unroll
    for (int cc = 0; cc < 32; cc++) Wr[cc] = W[cc * 32 + lane];
    size_t base = ((size_t)b * N0 + n) * 32;
    float t = HAS_SUB ? 2.f * a - sub[base + lane] : a;
    if (WRITE_TX) txout[base + lane] = t;
    float o = 0.f;
#pragma unroll
    for (int cc = 0; cc < 32; cc++) o += __shfl(t, cc, 32) * Wr[cc];
    accb[base + lane] += o;
}

// ---------------- dec1: project h through all six 32->3 W_k ----------------
__global__ void k_proj(const float* __restrict__ ACC, const float* __restrict__ W1,
                       float* __restrict__ G) {
    int lane = threadIdx.x & 31, nl = threadIdx.x >> 5;
    int n = blockIdx.x * 8 + nl;           // grid = N0/8 exactly
    int k = (lane < 18) ? lane / 3 : 0;
    int c = (lane < 18) ? lane % 3 : 0;
    float Wr[32];
#pragma unroll
    for (int cc = 0; cc < 32; cc++) Wr[cc] = W1[k * 96 + cc * 3 + c];
#pragma unroll
    for (int b = 0; b < B; b++) {
        float t = fmaxf(ACC[((size_t)b * N0 + n) * 32 + lane], 0.f);
        float o = 0.f;
#pragma unroll
        for (int cc = 0; cc < 32; cc++) o += __shfl(t, cc, 32) * Wr[cc];
        if (lane < 18) G[(size_t)k * BN4 + ((size_t)b * N0 + n) * 4 + c] = o;
    }
}

// ---------------- launch ----------------
extern "C" void kernel_launch(void* const* d_in, const int* in_sizes, int n_in,
                              void* d_out, int out_size, void* d_ws, size_t ws_size,
                              hipStream_t stream) {
    const float* x        = (const float*)d_in[0];
    const int*   ei       = (const int*)d_in[1];
    const float* A_norm   = (const float*)d_in[2];
    const int*   down_idx = (const int*)d_in[3];
    const float* down_val = (const float*)d_in[4];
    const int*   up_idx   = (const int*)d_in[5];
    const float* up_val   = (const float*)d_in[6];
    const float* W_enc0   = (const float*)d_in[7];
    const float* b_enc0   = (const float*)d_in[8];
    const float* W_dec0   = (const float*)d_in[9];
    const float* b_dec0   = (const float*)d_in[10];
    const float* W_dec1   = (const float*)d_in[11];
    const float* enc_lin_W = (const float*)d_in[12];
    const float* enc_lin_b = (const float*)d_in[13];
    const float* dec_lin_W = (const float*)d_in[14];
    const float* dec_lin_b = (const float*)d_in[15];
    float* OUT = (float*)d_out;

    char* w8 = (char*)d_ws;
    auto alignup = [](size_t v) { return (v + 255) & ~(size_t)255; };
    size_t off = 0;
    auto carve = [&](size_t bytes) { void* p = w8 + off; off = alignup(off + bytes); return p; };

    int*   row_ptr = (int*)carve((size_t)(N0 + 1) * 4);
    int*   poscnt  = (int*)carve((size_t)N0 * 4);
    int*   part    = (int*)carve(128 * 4);
    int*   col_s   = (int*)carve((size_t)E * 4);
    float* val_s   = (float*)carve((size_t)E * 4);
    float* zbuf    = (float*)carve((size_t)B * Z * 4);
    constexpr size_t BIG = (size_t)B * N0 * C;            // 12.8M floats
    float* A1 = (float*)carve(BIG * 4);
    float* A2 = (float*)carve(BIG * 4);
    float* A3 = (float*)carve(BIG * 4);
    (void)ws_size; (void)n_in; (void)in_sizes; (void)out_size;

    // aliases:
    float* T1 = A1 + 0 * BN4;   // padded encoder T buffers (32 MB in A1)
    float* T2 = A1 + 1 * BN4;
    float* T3 = A1 + 2 * BN4;
    float* T4 = A1 + 3 * BN4;
    float* T5 = A1 + 4 * BN4;
    float* HENC = A2;
    float* S0   = A3;
    float* PART = A2;           // enclin partials (12.8 MB), HENC dead by then
    float* P2   = A3 + (size_t)8 * 1024 * 1024;  // 100 KB at +32MB in A3
    float* S1   = A1;           // declin out [B,M]
    float* HUP  = A2;
    float* ACC  = A3;
    float* G    = A1;           // 6 x BN4 (38.4 MB) after dec0
    float* B4   = A2 + 0 * BN4; // Clenshaw b buffers
    float* B3   = A2 + 1 * BN4;
    float* B2   = A2 + 2 * BN4;
    float* B1   = A2 + 3 * BN4;

    const int* dcol = down_idx + DOWN_NNZ;
    const int* ucol = up_idx + UP_NNZ;

    dim3 blk(256);
    dim3 gE((E + 255) / 256);
    dim3 gN0t((N0 + 255) / 256);
    dim3 g3x(((N0 + 255) / 256) * 8);     // 1568, XCD-pinned: b = id & 7
    dim3 gN8(N0 / 8);                     // 6250, exact
    dim3 gNB(N0 / 8, B);
    dim3 gF(N0);                          // 50000: fused32 / pool3_init, b = id & 7
    dim3 gP4(((N1 + 7) / 8) * 8);         // 12504, b = id & 7

    // ---- CSR build over dst ----
    hipMemsetAsync(poscnt, 0, (size_t)N0 * 4, stream);
    k_hist<<<gE, blk, 0, stream>>>(ei + E, poscnt);
    int nchunks = (N0 + 511) / 512;
    k_scan_chunk<<<nchunks, 512, 0, stream>>>(poscnt, row_ptr, part);
    k_scan_part<<<1, 1, 0, stream>>>(part, nchunks);
    k_scan_add<<<gN0t, blk, 0, stream>>>(part, row_ptr, poscnt);
    k_scatter<<<gE, blk, 0, stream>>>(ei, A_norm, poscnt, col_s, val_s);

    // ---- encoder cheb (Cin=3), padded T buffers ----
    k_prop3g<3,3,4,false,false,false><<<g3x, blk, 0, stream>>>(row_ptr, col_s, val_s, x,  nullptr, nullptr, T1);
    k_prop3g<4,3,4,false,true, true ><<<g3x, blk, 0, stream>>>(row_ptr, col_s, val_s, T1, nullptr, x,  T2);
    k_prop3g<4,4,4,false,true, true ><<<g3x, blk, 0, stream>>>(row_ptr, col_s, val_s, T2, nullptr, T1, T3);
    k_prop3g<4,4,4,false,true, true ><<<g3x, blk, 0, stream>>>(row_ptr, col_s, val_s, T3, nullptr, T2, T4);
    k_prop3g<4,4,4,false,true, true ><<<g3x, blk, 0, stream>>>(row_ptr, col_s, val_s, T4, nullptr, T3, T5);
    k_enc_combine<<<gNB, blk, 0, stream>>>(x, T1, T2, T3, T4, T5, W_enc0, b_enc0, HENC);

    // ---- down pool ----
    k_pool4<<<gP4, blk, 0, stream>>>(dcol, down_val, HENC, S0);

    // ---- enc linear (split-K, parallel tree reduce) ----
    k_enclin1<<<3125, blk, 0, stream>>>(S0, enc_lin_W, PART);
    dim3 g2a(4, 25);
    k_enclin2a<<<g2a, blk, 0, stream>>>(PART, P2);
    k_enclin2b<<<4, blk, 0, stream>>>(P2, enc_lin_b, zbuf);

    // ---- dec linear ----
    k_declin<<<(M + 255) / 256, blk, 0, stream>>>(zbuf, dec_lin_W, dec_lin_b, S1);

    // ---- up pool fused with dec0 k=0 conv ----
    k_pool3_init<<<gF, blk, 0, stream>>>(ucol, up_val, S1, W_dec0, b_dec0, HUP, ACC);

    // ---- dec0 cheb (32->32), batch-split, XCD-pinned; rotate A2<->A1, ACC=A3 ----
    k_prop_fused32<false, true ><<<gF, blk, 0, stream>>>(row_ptr, col_s, val_s, A2, nullptr, A1, W_dec0 + 1 * C * C, ACC);
    k_prop_fused32<true,  true ><<<gF, blk, 0, stream>>>(row_ptr, col_s, val_s, A1, A2, A2, W_dec0 + 2 * C * C, ACC);
    k_prop_fused32<true,  true ><<<gF, blk, 0, stream>>>(row_ptr, col_s, val_s, A2, A1, A1, W_dec0 + 3 * C * C, ACC);
    k_prop_fused32<true,  true ><<<gF, blk, 0, stream>>>(row_ptr, col_s, val_s, A1, A2, A2, W_dec0 + 4 * C * C, ACC);
    k_prop_fused32<true,  false><<<gF, blk, 0, stream>>>(row_ptr, col_s, val_s, A2, A1, nullptr, W_dec0 + 5 * C * C, ACC);

    // ---- dec1 via Clenshaw in 3-channel space ----
    k_proj<<<gN8, blk, 0, stream>>>(ACC, W_dec1, G);
    float* G0 = G + 0 * BN4; float* G1 = G + 1 * BN4; float* G2 = G + 2 * BN4;
    float* G3c = G + 3 * BN4; float* G4 = G + 4 * BN4; float* G5 = G + 5 * BN4;
    // b5 = G5; b4 = G4 + 2L b5; b3 = G3 + 2L b4 - b5; b2..; b1..
    k_prop3g<4,4,4,true,false,true ><<<g3x, blk, 0, stream>>>(row_ptr, col_s, val_s, G5, G4, nullptr, B4);
    k_prop3g<4,4,4,true,true, true ><<<g3x, blk, 0, stream>>>(row_ptr, col_s, val_s, B4, G3c, G5, B3);
    k_prop3g<4,4,4,true,true, true ><<<g3x, blk, 0, stream>>>(row_ptr, col_s, val_s, B3, G2, B4, B2);
    k_prop3g<4,4,4,true,true, true ><<<g3x, blk, 0, stream>>>(row_ptr, col_s, val_s, B2, G1, B3, B1);
    // out = G0 + L b1 - b2   (scale 1)
    k_prop3g<4,4,3,true,true, false><<<g3x, blk, 0, stream>>>(row_ptr, col_s, val_s, B1, G0, B2, OUT);
}

// Round 4
// 1636.106 us; speedup vs baseline: 1.2564x; 1.0113x over previous
//
#include <hip/hip_runtime.h>

// ---- problem constants ----
constexpr int B   = 8;
constexpr int N0  = 50000;
constexpr int N1  = 12500;
constexpr int E   = 400000;
constexpr int FIN = 3;
constexpr int C   = 32;
constexpr int Z   = 128;
constexpr int M   = N1 * C;        // 400000
constexpr int DOWN_NNZ = N1 * 4;
constexpr int UP_NNZ   = N0 * 3;
constexpr size_t BN4 = (size_t)B * N0 * 4;   // padded 3-ch buffer stride (floats)

// ---------------- CSR build (over dst) ----------------
__global__ void k_hist(const int* __restrict__ dst, int* __restrict__ cnt) {
    int e = blockIdx.x * 256 + threadIdx.x;
    if (e < E) atomicAdd(&cnt[dst[e]], 1);
}

__global__ void k_scan_chunk(const int* __restrict__ cnt, int* __restrict__ rp,
                             int* __restrict__ part) {
    __shared__ int s[512];
    int t = threadIdx.x;
    int i = blockIdx.x * 512 + t;
    int v = (i < N0) ? cnt[i] : 0;
    s[t] = v;
    __syncthreads();
    for (int off = 1; off < 512; off <<= 1) {
        int add = (t >= off) ? s[t - off] : 0;
        __syncthreads();
        s[t] += add;
        __syncthreads();
    }
    if (i < N0) rp[i] = s[t] - v;
    if (t == 511) part[blockIdx.x] = s[511];
}

__global__ void k_scan_part(int* part, int nb) {
    if (threadIdx.x == 0 && blockIdx.x == 0) {
        int run = 0;
        for (int c = 0; c < nb; c++) { int t = part[c]; part[c] = run; run += t; }
    }
}

__global__ void k_scan_add(const int* __restrict__ part, int* __restrict__ rp,
                           int* __restrict__ pos) {
    int i = blockIdx.x * 256 + threadIdx.x;
    if (i < N0) {
        int r = rp[i] + part[i >> 9];
        rp[i] = r; pos[i] = r;
        if (i == 0) rp[N0] = E;
    }
}

__global__ void k_scatter(const int* __restrict__ ei, const float* __restrict__ norm,
                          int* __restrict__ pos, int* __restrict__ col_s,
                          float* __restrict__ val_s) {
    int e = blockIdx.x * 256 + threadIdx.x;
    if (e < E) {
        int d = ei[E + e];
        int j = atomicAdd(&pos[d], 1);
        col_s[j] = ei[e];
        val_s[j] = norm[e];
    }
}

// ---------------- generic 3-channel propagate (XCD-pinned: b = blockIdx.x & 7) ----------------
// out = [g] + (SCALE2?2:1)*prop(src) - [sub];  strides: SSTR/USTR/OSTR in {3,4}
// width-8 predicated gather round: 8 independent gathers in flight for EVERY row
template <int SSTR, int USTR, int OSTR, bool HAS_G, bool HAS_SUB, bool SCALE2>
__global__ void k_prop3g(const int* __restrict__ rp, const int* __restrict__ col,
                         const float* __restrict__ val, const float* __restrict__ src,
                         const float* __restrict__ g, const float* __restrict__ sub,
                         float* __restrict__ out) {
    int bid = blockIdx.x;
    int b = bid & 7;
    int n = (bid >> 3) * 256 + threadIdx.x;
    if (n >= N0) return;
    const float* sb = src + (size_t)b * N0 * SSTR;
    int s = rp[n], e = rp[n + 1];
    float x0[8], x1[8], x2[8];
#pragma unroll
    for (int u = 0; u < 8; u++) { x0[u] = 0.f; x1[u] = 0.f; x2[u] = 0.f; }
    for (int base = s; base < e; base += 8) {
        int jc[8]; float wv[8];
#pragma unroll
        for (int u = 0; u < 8; u++) {
            int jj = base + u;
            bool p = jj < e;
            int ji = p ? jj : s;
            jc[u] = col[ji];
            wv[u] = p ? val[ji] : 0.f;
        }
#pragma unroll
        for (int u = 0; u < 8; u++) {
            if (SSTR == 4) {
                float4 v = *(const float4*)(sb + (size_t)jc[u] * 4);
                x0[u] += wv[u] * v.x; x1[u] += wv[u] * v.y; x2[u] += wv[u] * v.z;
            } else {
                const float* p = sb + (size_t)jc[u] * 3;
                x0[u] += wv[u] * p[0]; x1[u] += wv[u] * p[1]; x2[u] += wv[u] * p[2];
            }
        }
    }
    float a0 = ((x0[0] + x0[1]) + (x0[2] + x0[3])) + ((x0[4] + x0[5]) + (x0[6] + x0[7]));
    float a1 = ((x1[0] + x1[1]) + (x1[2] + x1[3])) + ((x1[4] + x1[5]) + (x1[6] + x1[7]));
    float a2 = ((x2[0] + x2[1]) + (x2[2] + x2[3])) + ((x2[4] + x2[5]) + (x2[6] + x2[7]));
    if (SCALE2) { a0 *= 2.f; a1 *= 2.f; a2 *= 2.f; }
    if (HAS_G) {
        const float* gp = g + ((size_t)b * N0 + n) * 4;
        a0 += gp[0]; a1 += gp[1]; a2 += gp[2];
    }
    if (HAS_SUB) {
        const float* up = sub + ((size_t)b * N0 + n) * USTR;
        a0 -= up[0]; a1 -= up[1]; a2 -= up[2];
    }
    if (OSTR == 4) {
        *(float4*)(out + ((size_t)b * N0 + n) * 4) = make_float4(a0, a1, a2, 0.f);
    } else {
        float* op = out + ((size_t)b * N0 + n) * 3;
        op[0] = a0; op[1] = a1; op[2] = a2;
    }
}

// encoder combine: h = relu(b + sum_k T_k @ W_k); x stride 3, T stride 4
__global__ void k_enc_combine(const float* __restrict__ x,
                              const float* __restrict__ T1, const float* __restrict__ T2,
                              const float* __restrict__ T3, const float* __restrict__ T4,
                              const float* __restrict__ T5,
                              const float* __restrict__ W, const float* __restrict__ bias,
                              float* __restrict__ out) {
    int o = threadIdx.x & 31, nl = threadIdx.x >> 5;
    int n = blockIdx.x * 8 + nl;
    int b = blockIdx.y;
    size_t b3 = ((size_t)b * N0 + n) * 3;
    size_t b4 = ((size_t)b * N0 + n) * 4;
    float t[18];
    t[0] = x[b3 + 0]; t[1] = x[b3 + 1]; t[2] = x[b3 + 2];
    const float* Ts[5] = { T1, T2, T3, T4, T5 };
#pragma unroll
    for (int k = 0; k < 5; k++) {
        t[3 + k * 3 + 0] = Ts[k][b4 + 0];
        t[3 + k * 3 + 1] = Ts[k][b4 + 1];
        t[3 + k * 3 + 2] = Ts[k][b4 + 2];
    }
    float acc = bias[o];
#pragma unroll
    for (int q = 0; q < 18; q++) acc += t[q] * W[q * 32 + o];
    out[((size_t)b * N0 + n) * 32 + o] = fmaxf(acc, 0.f);
}

// ---------------- pools (XCD-pinned 1-D grids) ----------------
__global__ void k_pool4(const int* __restrict__ dcol, const float* __restrict__ dval,
                        const float* __restrict__ src, float* __restrict__ out) {
    int bid = blockIdx.x;
    int b = bid & 7;
    int c = threadIdx.x & 31, rl = threadIdx.x >> 5;
    int r = (bid >> 3) * 8 + rl;
    if (r >= N1) return;
    const float* sb = src + (size_t)b * N0 * 32;
    float a = 0.f;
#pragma unroll
    for (int t = 0; t < 4; t++) {
        int idx = 4 * r + t;
        a += dval[idx] * sb[(size_t)dcol[idx] * 32 + c];
    }
    out[((size_t)b * N1 + r) * 32 + c] = a;
}

// up-pool fused with dec0 k=0 conv: hup = P_up @ S1; acc = bias + hup @ W0
__global__ void k_pool3_init(const int* __restrict__ ucol, const float* __restrict__ uval,
                             const float* __restrict__ src, const float* __restrict__ W,
                             const float* __restrict__ bias,
                             float* __restrict__ hup, float* __restrict__ acc) {
    int bid = blockIdx.x;              // grid = 6250*8 exact
    int b = bid & 7;
    int c = threadIdx.x & 31, rl = threadIdx.x >> 5;
    int i = (bid >> 3) * 8 + rl;
    const float* sb = src + (size_t)b * N1 * 32;
    float a = 0.f;
#pragma unroll
    for (int t = 0; t < 3; t++) {
        int idx = 3 * i + t;
        a += uval[idx] * sb[(size_t)ucol[idx] * 32 + c];
    }
    size_t base = ((size_t)b * N0 + i) * 32;
    hup[base + c] = a;
    float Wr[32];
#pragma unroll
    for (int cc = 0; cc < 32; cc++) Wr[cc] = W[cc * 32 + c];
    float o0 = bias[c], o1 = 0.f, o2 = 0.f, o3 = 0.f;
#pragma unroll
    for (int cc = 0; cc < 32; cc += 4) {
        o0 += __shfl(a, cc, 32) * Wr[cc];
        o1 += __shfl(a, cc + 1, 32) * Wr[cc + 1];
        o2 += __shfl(a, cc + 2, 32) * Wr[cc + 2];
        o3 += __shfl(a, cc + 3, 32) * Wr[cc + 3];
    }
    acc[base + c] = (o0 + o1) + (o2 + o3);
}

// ---------------- enc linear: split-K two stage ----------------
__global__ void k_enclin1(const float* __restrict__ S0, const float* __restrict__ W,
                          float* __restrict__ partial) {
    int zl = threadIdx.x & 127, half = threadIdx.x >> 7;
    int m0 = blockIdx.x * 128;
    float acc[B];
#pragma unroll
    for (int b = 0; b < B; b++) acc[b] = 0.f;
    for (int i = 0; i < 64; i++) {
        int m = m0 + half + 2 * i;
        float w = W[(size_t)m * Z + zl];
#pragma unroll
        for (int b = 0; b < B; b++) acc[b] += S0[(size_t)b * M + m] * w;
    }
    __shared__ float red[128 * B];
    if (half == 1) {
#pragma unroll
        for (int b = 0; b < B; b++) red[zl * B + b] = acc[b];
    }
    __syncthreads();
    if (half == 0) {
#pragma unroll
        for (int b = 0; b < B; b++)
            partial[(size_t)blockIdx.x * 1024 + b * 128 + zl] = acc[b] + red[zl * B + b];
    }
}

// stage 2a: tree-reduce partials across k, coalesced along i.
__global__ void k_enclin2a(const float* __restrict__ partial, float* __restrict__ p2) {
    int i  = blockIdx.x * 256 + threadIdx.x;   // 0..1023
    int kc = blockIdx.y;                       // 0..24
    int k0 = kc * 125;
    float a = 0.f;
    for (int k = k0; k < k0 + 125; k++) a += partial[(size_t)k * 1024 + i];
    p2[(size_t)kc * 1024 + i] = a;
}

__global__ void k_enclin2b(const float* __restrict__ p2, const float* __restrict__ bias,
                           float* __restrict__ z) {
    int i = blockIdx.x * 256 + threadIdx.x;
    if (i >= B * Z) return;
    float a = bias[i & 127];
#pragma unroll
    for (int k = 0; k < 25; k++) a += p2[(size_t)k * 1024 + i];
    z[i] = a;
}

__global__ void k_declin(const float* __restrict__ z, const float* __restrict__ W,
                         const float* __restrict__ bias, float* __restrict__ out) {
    __shared__ float zs[B * Z];
    for (int i = threadIdx.x; i < B * Z; i += 256) zs[i] = z[i];
    __syncthreads();
    int m = blockIdx.x * 256 + threadIdx.x;
    if (m >= M) return;
    float bv = bias[m];
    float acc[B];
#pragma unroll
    for (int b = 0; b < B; b++) acc[b] = bv;
    for (int j = 0; j < Z; j++) {
        float w = W[(size_t)j * M + m];
#pragma unroll
        for (int b = 0; b < B; b++) acc[b] += zs[b * Z + j] * w;
    }
#pragma unroll
    for (int b = 0; b < B; b++) out[(size_t)b * M + m] = fmaxf(acc[b], 0.f);
}

// ---------------- dec0: propagate + conv, batch-split & XCD-pinned, width-8 MLP ----------------
// grid = 50000 (6250 n-blocks x 8 batches); XCD(id) = id%8 == b
template <bool HAS_SUB, bool WRITE_TX>
__global__ void k_prop_fused32(const int* __restrict__ rp, const int* __restrict__ col,
                               const float* __restrict__ val, const float* __restrict__ src,
                               const float* __restrict__ sub, float* __restrict__ txout,
                               const float* __restrict__ W, float* __restrict__ accb) {
    int bid = blockIdx.x;
    int b = bid & 7;
    int lane = threadIdx.x & 31, nl = threadIdx.x >> 5;
    int n = (bid >> 3) * 8 + nl;           // exact
    int s = rp[n], e = rp[n + 1];
    const float* sb = src + (size_t)b * N0 * 32;
    float acc[8];
#pragma unroll
    for (int u = 0; u < 8; u++) acc[u] = 0.f;
    for (int base = s; base < e; base += 8) {
        int jc[8]; float wv[8];
#pragma unroll
        for (int u = 0; u < 8; u++) {
            int jj = base + u;
            bool p = jj < e;
            int ji = p ? jj : s;
            jc[u] = col[ji];
            wv[u] = p ? val[ji] : 0.f;
        }
#pragma unroll
        for (int u = 0; u < 8; u++)
            acc[u] += wv[u] * sb[(size_t)jc[u] * 32 + lane];
    }
    float a = ((acc[0] + acc[1]) + (acc[2] + acc[3])) + ((acc[4] + acc[5]) + (acc[6] + acc[7]));
    float Wr[32];
#pragma unroll
    for (int cc = 0; cc < 32; cc++) Wr[cc] = W[cc * 32 + lane];
    size_t base2 = ((size_t)b * N0 + n) * 32;
    float t = HAS_SUB ? 2.f * a - sub[base2 + lane] : a;
    if (WRITE_TX) txout[base2 + lane] = t;
    float o0 = 0.f, o1 = 0.f, o2 = 0.f, o3 = 0.f;
#pragma unroll
    for (int cc = 0; cc < 32; cc += 4) {
        o0 += __shfl(t, cc, 32) * Wr[cc];
        o1 += __shfl(t, cc + 1, 32) * Wr[cc + 1];
        o2 += __shfl(t, cc + 2, 32) * Wr[cc + 2];
        o3 += __shfl(t, cc + 3, 32) * Wr[cc + 3];
    }
    accb[base2 + lane] += (o0 + o1) + (o2 + o3);
}

// ---------------- dec1: project h through all six 32->3 W_k ----------------
__global__ void k_proj(const float* __restrict__ ACC, const float* __restrict__ W1,
                       float* __restrict__ G) {
    int lane = threadIdx.x & 31, nl = threadIdx.x >> 5;
    int n = blockIdx.x * 8 + nl;           // grid = N0/8 exactly
    int k = (lane < 18) ? lane / 3 : 0;
    int c = (lane < 18) ? lane % 3 : 0;
    float Wr[32];
#pragma unroll
    for (int cc = 0; cc < 32; cc++) Wr[cc] = W1[k * 96 + cc * 3 + c];
#pragma unroll
    for (int b = 0; b < B; b++) {
        float t = fmaxf(ACC[((size_t)b * N0 + n) * 32 + lane], 0.f);
        float o0 = 0.f, o1 = 0.f, o2 = 0.f, o3 = 0.f;
#pragma unroll
        for (int cc = 0; cc < 32; cc += 4) {
            o0 += __shfl(t, cc, 32) * Wr[cc];
            o1 += __shfl(t, cc + 1, 32) * Wr[cc + 1];
            o2 += __shfl(t, cc + 2, 32) * Wr[cc + 2];
            o3 += __shfl(t, cc + 3, 32) * Wr[cc + 3];
        }
        if (lane < 18)
            G[(size_t)k * BN4 + ((size_t)b * N0 + n) * 4 + c] = (o0 + o1) + (o2 + o3);
    }
}

// ---------------- launch ----------------
extern "C" void kernel_launch(void* const* d_in, const int* in_sizes, int n_in,
                              void* d_out, int out_size, void* d_ws, size_t ws_size,
                              hipStream_t stream) {
    const float* x        = (const float*)d_in[0];
    const int*   ei       = (const int*)d_in[1];
    const float* A_norm   = (const float*)d_in[2];
    const int*   down_idx = (const int*)d_in[3];
    const float* down_val = (const float*)d_in[4];
    const int*   up_idx   = (const int*)d_in[5];
    const float* up_val   = (const float*)d_in[6];
    const float* W_enc0   = (const float*)d_in[7];
    const float* b_enc0   = (const float*)d_in[8];
    const float* W_dec0   = (const float*)d_in[9];
    const float* b_dec0   = (const float*)d_in[10];
    const float* W_dec1   = (const float*)d_in[11];
    const float* enc_lin_W = (const float*)d_in[12];
    const float* enc_lin_b = (const float*)d_in[13];
    const float* dec_lin_W = (const float*)d_in[14];
    const float* dec_lin_b = (const float*)d_in[15];
    float* OUT = (float*)d_out;

    char* w8 = (char*)d_ws;
    auto alignup = [](size_t v) { return (v + 255) & ~(size_t)255; };
    size_t off = 0;
    auto carve = [&](size_t bytes) { void* p = w8 + off; off = alignup(off + bytes); return p; };

    int*   row_ptr = (int*)carve((size_t)(N0 + 1) * 4);
    int*   poscnt  = (int*)carve((size_t)N0 * 4);
    int*   part    = (int*)carve(128 * 4);
    int*   col_s   = (int*)carve((size_t)E * 4 + 64);   // +pad (predicated loads stay in-bounds anyway)
    float* val_s   = (float*)carve((size_t)E * 4 + 64);
    float* zbuf    = (float*)carve((size_t)B * Z * 4);
    constexpr size_t BIG = (size_t)B * N0 * C;            // 12.8M floats
    float* A1 = (float*)carve(BIG * 4);
    float* A2 = (float*)carve(BIG * 4);
    float* A3 = (float*)carve(BIG * 4);
    (void)ws_size; (void)n_in; (void)in_sizes; (void)out_size;

    // aliases:
    float* T1 = A1 + 0 * BN4;   // padded encoder T buffers (32 MB in A1)
    float* T2 = A1 + 1 * BN4;
    float* T3 = A1 + 2 * BN4;
    float* T4 = A1 + 3 * BN4;
    float* T5 = A1 + 4 * BN4;
    float* HENC = A2;
    float* S0   = A3;
    float* PART = A2;           // enclin partials (12.8 MB), HENC dead by then
    float* P2   = A3 + (size_t)8 * 1024 * 1024;  // 100 KB at +32MB in A3
    float* S1   = A1;           // declin out [B,M]
    float* HUP  = A2;
    float* ACC  = A3;
    float* G    = A1;           // 6 x BN4 (38.4 MB) after dec0
    float* B4   = A2 + 0 * BN4; // Clenshaw b buffers
    float* B3   = A2 + 1 * BN4;
    float* B2   = A2 + 2 * BN4;
    float* B1   = A2 + 3 * BN4;

    const int* dcol = down_idx + DOWN_NNZ;
    const int* ucol = up_idx + UP_NNZ;

    dim3 blk(256);
    dim3 gE((E + 255) / 256);
    dim3 gN0t((N0 + 255) / 256);
    dim3 g3x(((N0 + 255) / 256) * 8);     // 1568, XCD-pinned: b = id & 7
    dim3 gN8(N0 / 8);                     // 6250, exact
    dim3 gNB(N0 / 8, B);
    dim3 gF(N0);                          // 50000: fused32 / pool3_init, b = id & 7
    dim3 gP4(((N1 + 7) / 8) * 8);         // 12504, b = id & 7

    // ---- CSR build over dst ----
    hipMemsetAsync(poscnt, 0, (size_t)N0 * 4, stream);
    k_hist<<<gE, blk, 0, stream>>>(ei + E, poscnt);
    int nchunks = (N0 + 511) / 512;
    k_scan_chunk<<<nchunks, 512, 0, stream>>>(poscnt, row_ptr, part);
    k_scan_part<<<1, 1, 0, stream>>>(part, nchunks);
    k_scan_add<<<gN0t, blk, 0, stream>>>(part, row_ptr, poscnt);
    k_scatter<<<gE, blk, 0, stream>>>(ei, A_norm, poscnt, col_s, val_s);

    // ---- encoder cheb (Cin=3), padded T buffers ----
    k_prop3g<3,3,4,false,false,false><<<g3x, blk, 0, stream>>>(row_ptr, col_s, val_s, x,  nullptr, nullptr, T1);
    k_prop3g<4,3,4,false,true, true ><<<g3x, blk, 0, stream>>>(row_ptr, col_s, val_s, T1, nullptr, x,  T2);
    k_prop3g<4,4,4,false,true, true ><<<g3x, blk, 0, stream>>>(row_ptr, col_s, val_s, T2, nullptr, T1, T3);
    k_prop3g<4,4,4,false,true, true ><<<g3x, blk, 0, stream>>>(row_ptr, col_s, val_s, T3, nullptr, T2, T4);
    k_prop3g<4,4,4,false,true, true ><<<g3x, blk, 0, stream>>>(row_ptr, col_s, val_s, T4, nullptr, T3, T5);
    k_enc_combine<<<gNB, blk, 0, stream>>>(x, T1, T2, T3, T4, T5, W_enc0, b_enc0, HENC);

    // ---- down pool ----
    k_pool4<<<gP4, blk, 0, stream>>>(dcol, down_val, HENC, S0);

    // ---- enc linear (split-K, parallel tree reduce) ----
    k_enclin1<<<3125, blk, 0, stream>>>(S0, enc_lin_W, PART);
    dim3 g2a(4, 25);
    k_enclin2a<<<g2a, blk, 0, stream>>>(PART, P2);
    k_enclin2b<<<4, blk, 0, stream>>>(P2, enc_lin_b, zbuf);

    // ---- dec linear ----
    k_declin<<<(M + 255) / 256, blk, 0, stream>>>(zbuf, dec_lin_W, dec_lin_b, S1);

    // ---- up pool fused with dec0 k=0 conv ----
    k_pool3_init<<<gF, blk, 0, stream>>>(ucol, up_val, S1, W_dec0, b_dec0, HUP, ACC);

    // ---- dec0 cheb (32->32), batch-split, XCD-pinned; rotate A2<->A1, ACC=A3 ----
    k_prop_fused32<false, true ><<<gF, blk, 0, stream>>>(row_ptr, col_s, val_s, A2, nullptr, A1, W_dec0 + 1 * C * C, ACC);
    k_prop_fused32<true,  true ><<<gF, blk, 0, stream>>>(row_ptr, col_s, val_s, A1, A2, A2, W_dec0 + 2 * C * C, ACC);
    k_prop_fused32<true,  true ><<<gF, blk, 0, stream>>>(row_ptr, col_s, val_s, A2, A1, A1, W_dec0 + 3 * C * C, ACC);
    k_prop_fused32<true,  true ><<<gF, blk, 0, stream>>>(row_ptr, col_s, val_s, A1, A2, A2, W_dec0 + 4 * C * C, ACC);
    k_prop_fused32<true,  false><<<gF, blk, 0, stream>>>(row_ptr, col_s, val_s, A2, A1, nullptr, W_dec0 + 5 * C * C, ACC);

    // ---- dec1 via Clenshaw in 3-channel space ----
    k_proj<<<gN8, blk, 0, stream>>>(ACC, W_dec1, G);
    float* G0 = G + 0 * BN4; float* G1 = G + 1 * BN4; float* G2 = G + 2 * BN4;
    float* G3c = G + 3 * BN4; float* G4 = G + 4 * BN4; float* G5 = G + 5 * BN4;
    // b5 = G5; b4 = G4 + 2L b5; b3 = G3 + 2L b4 - b5; b2..; b1..
    k_prop3g<4,4,4,true,false,true ><<<g3x, blk, 0, stream>>>(row_ptr, col_s, val_s, G5, G4, nullptr, B4);
    k_prop3g<4,4,4,true,true, true ><<<g3x, blk, 0, stream>>>(row_ptr, col_s, val_s, B4, G3c, G5, B3);
    k_prop3g<4,4,4,true,true, true ><<<g3x, blk, 0, stream>>>(row_ptr, col_s, val_s, B3, G2, B4, B2);
    k_prop3g<4,4,4,true,true, true ><<<g3x, blk, 0, stream>>>(row_ptr, col_s, val_s, B2, G1, B3, B1);
    // out = G0 + L b1 - b2   (scale 1)
    k_prop3g<4,4,3,true,true, false><<<g3x, blk, 0, stream>>>(row_ptr, col_s, val_s, B1, G0, B2, OUT);
}

// Round 5
// 1477.628 us; speedup vs baseline: 1.3912x; 1.1073x over previous
//
#include <hip/hip_runtime.h>

// ---- problem constants ----
constexpr int B   = 8;
constexpr int N0  = 50000;
constexpr int N1  = 12500;
constexpr int E   = 400000;
constexpr int FIN = 3;
constexpr int C   = 32;
constexpr int Z   = 128;
constexpr int M   = N1 * C;        // 400000
constexpr int DOWN_NNZ = N1 * 4;
constexpr int UP_NNZ   = N0 * 3;
constexpr size_t BN4 = (size_t)B * N0 * 4;   // padded 3-ch buffer stride (floats)

// ---------------- CSR build (over dst) ----------------
__global__ void k_hist(const int* __restrict__ dst, int* __restrict__ cnt) {
    int e = blockIdx.x * 256 + threadIdx.x;
    if (e < E) atomicAdd(&cnt[dst[e]], 1);
}

__global__ void k_scan_chunk(const int* __restrict__ cnt, int* __restrict__ rp,
                             int* __restrict__ part) {
    __shared__ int s[512];
    int t = threadIdx.x;
    int i = blockIdx.x * 512 + t;
    int v = (i < N0) ? cnt[i] : 0;
    s[t] = v;
    __syncthreads();
    for (int off = 1; off < 512; off <<= 1) {
        int add = (t >= off) ? s[t - off] : 0;
        __syncthreads();
        s[t] += add;
        __syncthreads();
    }
    if (i < N0) rp[i] = s[t] - v;
    if (t == 511) part[blockIdx.x] = s[511];
}

__global__ void k_scan_part(int* part, int nb) {
    if (threadIdx.x == 0 && blockIdx.x == 0) {
        int run = 0;
        for (int c = 0; c < nb; c++) { int t = part[c]; part[c] = run; run += t; }
    }
}

__global__ void k_scan_add(const int* __restrict__ part, int* __restrict__ rp,
                           int* __restrict__ pos) {
    int i = blockIdx.x * 256 + threadIdx.x;
    if (i < N0) {
        int r = rp[i] + part[i >> 9];
        rp[i] = r; pos[i] = r;
        if (i == 0) rp[N0] = E;
    }
}

__global__ void k_scatter(const int* __restrict__ ei, const float* __restrict__ norm,
                          int* __restrict__ pos, int* __restrict__ col_s,
                          float* __restrict__ val_s) {
    int e = blockIdx.x * 256 + threadIdx.x;
    if (e < E) {
        int d = ei[E + e];
        int j = atomicAdd(&pos[d], 1);
        col_s[j] = ei[e];
        val_s[j] = norm[e];
    }
}

// ---------------- generic 3-channel propagate, batch-PAIR per thread ----------------
// grid = 196 n-chunks * 4 pairs = 784 blocks; pair q = bid & 3 -> batches (2q, 2q+1)
// XCD(bid)=bid%8: pair q lives on XCDs {q, q+4}; per-XCD gather slice = 1.6 MB (L2-fit)
// width-4 predicated rounds * 2 batches = 8 independent float4 gathers in flight
template <int SSTR, int USTR, int OSTR, bool HAS_G, bool HAS_SUB, bool SCALE2>
__global__ void k_prop3g(const int* __restrict__ rp, const int* __restrict__ col,
                         const float* __restrict__ val, const float* __restrict__ src,
                         const float* __restrict__ g, const float* __restrict__ sub,
                         float* __restrict__ out) {
    int bid = blockIdx.x;
    int q = bid & 3;
    int b0 = 2 * q, b1 = 2 * q + 1;
    int n = (bid >> 2) * 256 + threadIdx.x;
    if (n >= N0) return;
    const float* s0 = src + (size_t)b0 * N0 * SSTR;
    const float* s1 = src + (size_t)b1 * N0 * SSTR;
    int s = rp[n], e = rp[n + 1];
    float xa[4][3], xb[4][3];
#pragma unroll
    for (int u = 0; u < 4; u++)
#pragma unroll
        for (int c = 0; c < 3; c++) { xa[u][c] = 0.f; xb[u][c] = 0.f; }
    for (int base = s; base < e; base += 4) {
        int jc[4]; float wv[4];
#pragma unroll
        for (int u = 0; u < 4; u++) {
            int jj = base + u;
            bool p = jj < e;
            int ji = p ? jj : s;
            jc[u] = col[ji];
            wv[u] = p ? val[ji] : 0.f;
        }
#pragma unroll
        for (int u = 0; u < 4; u++) {
            if (SSTR == 4) {
                float4 va = *(const float4*)(s0 + (size_t)jc[u] * 4);
                float4 vb = *(const float4*)(s1 + (size_t)jc[u] * 4);
                xa[u][0] += wv[u] * va.x; xa[u][1] += wv[u] * va.y; xa[u][2] += wv[u] * va.z;
                xb[u][0] += wv[u] * vb.x; xb[u][1] += wv[u] * vb.y; xb[u][2] += wv[u] * vb.z;
            } else {
                const float* pa = s0 + (size_t)jc[u] * 3;
                const float* pb = s1 + (size_t)jc[u] * 3;
                xa[u][0] += wv[u] * pa[0]; xa[u][1] += wv[u] * pa[1]; xa[u][2] += wv[u] * pa[2];
                xb[u][0] += wv[u] * pb[0]; xb[u][1] += wv[u] * pb[1]; xb[u][2] += wv[u] * pb[2];
            }
        }
    }
#pragma unroll
    for (int half = 0; half < 2; half++) {
        int b = half ? b1 : b0;
        float (*x)[3] = half ? xb : xa;
        float a0 = (x[0][0] + x[1][0]) + (x[2][0] + x[3][0]);
        float a1 = (x[0][1] + x[1][1]) + (x[2][1] + x[3][1]);
        float a2 = (x[0][2] + x[1][2]) + (x[2][2] + x[3][2]);
        if (SCALE2) { a0 *= 2.f; a1 *= 2.f; a2 *= 2.f; }
        if (HAS_G) {
            const float* gp = g + ((size_t)b * N0 + n) * 4;
            a0 += gp[0]; a1 += gp[1]; a2 += gp[2];
        }
        if (HAS_SUB) {
            const float* up = sub + ((size_t)b * N0 + n) * USTR;
            a0 -= up[0]; a1 -= up[1]; a2 -= up[2];
        }
        if (OSTR == 4) {
            *(float4*)(out + ((size_t)b * N0 + n) * 4) = make_float4(a0, a1, a2, 0.f);
        } else {
            float* op = out + ((size_t)b * N0 + n) * 3;
            op[0] = a0; op[1] = a1; op[2] = a2;
        }
    }
}

// encoder combine: h = relu(b + sum_k T_k @ W_k); x stride 3, T stride 4
__global__ void k_enc_combine(const float* __restrict__ x,
                              const float* __restrict__ T1, const float* __restrict__ T2,
                              const float* __restrict__ T3, const float* __restrict__ T4,
                              const float* __restrict__ T5,
                              const float* __restrict__ W, const float* __restrict__ bias,
                              float* __restrict__ out) {
    int o = threadIdx.x & 31, nl = threadIdx.x >> 5;
    int n = blockIdx.x * 8 + nl;
    int b = blockIdx.y;
    size_t b3 = ((size_t)b * N0 + n) * 3;
    size_t b4 = ((size_t)b * N0 + n) * 4;
    float t[18];
    t[0] = x[b3 + 0]; t[1] = x[b3 + 1]; t[2] = x[b3 + 2];
    const float* Ts[5] = { T1, T2, T3, T4, T5 };
#pragma unroll
    for (int k = 0; k < 5; k++) {
        t[3 + k * 3 + 0] = Ts[k][b4 + 0];
        t[3 + k * 3 + 1] = Ts[k][b4 + 1];
        t[3 + k * 3 + 2] = Ts[k][b4 + 2];
    }
    float acc = bias[o];
#pragma unroll
    for (int q = 0; q < 18; q++) acc += t[q] * W[q * 32 + o];
    out[((size_t)b * N0 + n) * 32 + o] = fmaxf(acc, 0.f);
}

// ---------------- pools (XCD-pinned 1-D grids) ----------------
__global__ void k_pool4(const int* __restrict__ dcol, const float* __restrict__ dval,
                        const float* __restrict__ src, float* __restrict__ out) {
    int bid = blockIdx.x;
    int b = bid & 7;
    int c = threadIdx.x & 31, rl = threadIdx.x >> 5;
    int r = (bid >> 3) * 8 + rl;
    if (r >= N1) return;
    const float* sb = src + (size_t)b * N0 * 32;
    float a = 0.f;
#pragma unroll
    for (int t = 0; t < 4; t++) {
        int idx = 4 * r + t;
        a += dval[idx] * sb[(size_t)dcol[idx] * 32 + c];
    }
    out[((size_t)b * N1 + r) * 32 + c] = a;
}

// up-pool fused with dec0 k=0 conv: hup = P_up @ S1; acc = bias + hup @ W0
__global__ void k_pool3_init(const int* __restrict__ ucol, const float* __restrict__ uval,
                             const float* __restrict__ src, const float* __restrict__ W,
                             const float* __restrict__ bias,
                             float* __restrict__ hup, float* __restrict__ acc) {
    int bid = blockIdx.x;              // grid = 6250*8 exact
    int b = bid & 7;
    int c = threadIdx.x & 31, rl = threadIdx.x >> 5;
    int i = (bid >> 3) * 8 + rl;
    const float* sb = src + (size_t)b * N1 * 32;
    float a = 0.f;
#pragma unroll
    for (int t = 0; t < 3; t++) {
        int idx = 3 * i + t;
        a += uval[idx] * sb[(size_t)ucol[idx] * 32 + c];
    }
    size_t base = ((size_t)b * N0 + i) * 32;
    hup[base + c] = a;
    float Wr[32];
#pragma unroll
    for (int cc = 0; cc < 32; cc++) Wr[cc] = W[cc * 32 + c];
    float o0 = bias[c], o1 = 0.f, o2 = 0.f, o3 = 0.f;
#pragma unroll
    for (int cc = 0; cc < 32; cc += 4) {
        o0 += __shfl(a, cc, 32) * Wr[cc];
        o1 += __shfl(a, cc + 1, 32) * Wr[cc + 1];
        o2 += __shfl(a, cc + 2, 32) * Wr[cc + 2];
        o3 += __shfl(a, cc + 3, 32) * Wr[cc + 3];
    }
    acc[base + c] = (o0 + o1) + (o2 + o3);
}

// ---------------- enc linear: split-K two stage ----------------
__global__ void k_enclin1(const float* __restrict__ S0, const float* __restrict__ W,
                          float* __restrict__ partial) {
    int zl = threadIdx.x & 127, half = threadIdx.x >> 7;
    int m0 = blockIdx.x * 128;
    float acc[B];
#pragma unroll
    for (int b = 0; b < B; b++) acc[b] = 0.f;
    for (int i = 0; i < 64; i++) {
        int m = m0 + half + 2 * i;
        float w = W[(size_t)m * Z + zl];
#pragma unroll
        for (int b = 0; b < B; b++) acc[b] += S0[(size_t)b * M + m] * w;
    }
    __shared__ float red[128 * B];
    if (half == 1) {
#pragma unroll
        for (int b = 0; b < B; b++) red[zl * B + b] = acc[b];
    }
    __syncthreads();
    if (half == 0) {
#pragma unroll
        for (int b = 0; b < B; b++)
            partial[(size_t)blockIdx.x * 1024 + b * 128 + zl] = acc[b] + red[zl * B + b];
    }
}

// stage 2a: tree-reduce partials across k, coalesced along i.
__global__ void k_enclin2a(const float* __restrict__ partial, float* __restrict__ p2) {
    int i  = blockIdx.x * 256 + threadIdx.x;   // 0..1023
    int kc = blockIdx.y;                       // 0..24
    int k0 = kc * 125;
    float a = 0.f;
    for (int k = k0; k < k0 + 125; k++) a += partial[(size_t)k * 1024 + i];
    p2[(size_t)kc * 1024 + i] = a;
}

__global__ void k_enclin2b(const float* __restrict__ p2, const float* __restrict__ bias,
                           float* __restrict__ z) {
    int i = blockIdx.x * 256 + threadIdx.x;
    if (i >= B * Z) return;
    float a = bias[i & 127];
#pragma unroll
    for (int k = 0; k < 25; k++) a += p2[(size_t)k * 1024 + i];
    z[i] = a;
}

__global__ void k_declin(const float* __restrict__ z, const float* __restrict__ W,
                         const float* __restrict__ bias, float* __restrict__ out) {
    __shared__ float zs[B * Z];
    for (int i = threadIdx.x; i < B * Z; i += 256) zs[i] = z[i];
    __syncthreads();
    int m = blockIdx.x * 256 + threadIdx.x;
    if (m >= M) return;
    float bv = bias[m];
    float acc[B];
#pragma unroll
    for (int b = 0; b < B; b++) acc[b] = bv;
    for (int j = 0; j < Z; j++) {
        float w = W[(size_t)j * M + m];
#pragma unroll
        for (int b = 0; b < B; b++) acc[b] += zs[b * Z + j] * w;
    }
#pragma unroll
    for (int b = 0; b < B; b++) out[(size_t)b * M + m] = fmaxf(acc[b], 0.f);
}

// ---------------- dec0: propagate + conv, batch-VECTORED (a[8]) ----------------
// grid = N0/8 = 6250 blocks; per edge: col/val/voffset computed ONCE, then
// 8x {sgpr-base add + load + fma}. width-2 unroll -> 16 independent loads in flight.
template <bool HAS_SUB, bool WRITE_TX>
__global__ void k_prop_fused32(const int* __restrict__ rp, const int* __restrict__ col,
                               const float* __restrict__ val, const float* __restrict__ src,
                               const float* __restrict__ sub, float* __restrict__ txout,
                               const float* __restrict__ W, float* __restrict__ accb) {
    int lane = threadIdx.x & 31, nl = threadIdx.x >> 5;
    int n = blockIdx.x * 8 + nl;           // grid = N0/8 exact
    int s = rp[n], e = rp[n + 1];
    float accA[B], accB2[B];
#pragma unroll
    for (int b = 0; b < B; b++) { accA[b] = 0.f; accB2[b] = 0.f; }
    for (int base = s; base < e; base += 2) {
        bool p1 = base + 1 < e;
        int c0 = col[base];
        int c1 = col[p1 ? base + 1 : base];
        float w0 = val[base];
        float w1 = p1 ? val[base + 1] : 0.f;
        size_t o0 = (size_t)c0 * 32 + lane;
        size_t o1 = (size_t)c1 * 32 + lane;
#pragma unroll
        for (int b = 0; b < B; b++) {
            const float* sb = src + (size_t)b * (N0 * 32);
            accA[b]  += w0 * sb[o0];
            accB2[b] += w1 * sb[o1];
        }
    }
    float Wr[32];
#pragma unroll
    for (int cc = 0; cc < 32; cc++) Wr[cc] = W[cc * 32 + lane];
#pragma unroll
    for (int b = 0; b < B; b++) {
        float a = accA[b] + accB2[b];
        size_t base2 = ((size_t)b * N0 + n) * 32;
        float t = HAS_SUB ? 2.f * a - sub[base2 + lane] : a;
        if (WRITE_TX) txout[base2 + lane] = t;
        float o0 = 0.f, o1 = 0.f, o2 = 0.f, o3 = 0.f;
#pragma unroll
        for (int cc = 0; cc < 32; cc += 4) {
            o0 += __shfl(t, cc, 32) * Wr[cc];
            o1 += __shfl(t, cc + 1, 32) * Wr[cc + 1];
            o2 += __shfl(t, cc + 2, 32) * Wr[cc + 2];
            o3 += __shfl(t, cc + 3, 32) * Wr[cc + 3];
        }
        accb[base2 + lane] += (o0 + o1) + (o2 + o3);
    }
}

// ---------------- dec1: project h through all six 32->3 W_k ----------------
__global__ void k_proj(const float* __restrict__ ACC, const float* __restrict__ W1,
                       float* __restrict__ G) {
    int lane = threadIdx.x & 31, nl = threadIdx.x >> 5;
    int n = blockIdx.x * 8 + nl;           // grid = N0/8 exactly
    int k = (lane < 18) ? lane / 3 : 0;
    int c = (lane < 18) ? lane % 3 : 0;
    float Wr[32];
#pragma unroll
    for (int cc = 0; cc < 32; cc++) Wr[cc] = W1[k * 96 + cc * 3 + c];
#pragma unroll
    for (int b = 0; b < B; b++) {
        float t = fmaxf(ACC[((size_t)b * N0 + n) * 32 + lane], 0.f);
        float o0 = 0.f, o1 = 0.f, o2 = 0.f, o3 = 0.f;
#pragma unroll
        for (int cc = 0; cc < 32; cc += 4) {
            o0 += __shfl(t, cc, 32) * Wr[cc];
            o1 += __shfl(t, cc + 1, 32) * Wr[cc + 1];
            o2 += __shfl(t, cc + 2, 32) * Wr[cc + 2];
            o3 += __shfl(t, cc + 3, 32) * Wr[cc + 3];
        }
        if (lane < 18)
            G[(size_t)k * BN4 + ((size_t)b * N0 + n) * 4 + c] = (o0 + o1) + (o2 + o3);
    }
}

// ---------------- launch ----------------
extern "C" void kernel_launch(void* const* d_in, const int* in_sizes, int n_in,
                              void* d_out, int out_size, void* d_ws, size_t ws_size,
                              hipStream_t stream) {
    const float* x        = (const float*)d_in[0];
    const int*   ei       = (const int*)d_in[1];
    const float* A_norm   = (const float*)d_in[2];
    const int*   down_idx = (const int*)d_in[3];
    const float* down_val = (const float*)d_in[4];
    const int*   up_idx   = (const int*)d_in[5];
    const float* up_val   = (const float*)d_in[6];
    const float* W_enc0   = (const float*)d_in[7];
    const float* b_enc0   = (const float*)d_in[8];
    const float* W_dec0   = (const float*)d_in[9];
    const float* b_dec0   = (const float*)d_in[10];
    const float* W_dec1   = (const float*)d_in[11];
    const float* enc_lin_W = (const float*)d_in[12];
    const float* enc_lin_b = (const float*)d_in[13];
    const float* dec_lin_W = (const float*)d_in[14];
    const float* dec_lin_b = (const float*)d_in[15];
    float* OUT = (float*)d_out;

    char* w8 = (char*)d_ws;
    auto alignup = [](size_t v) { return (v + 255) & ~(size_t)255; };
    size_t off = 0;
    auto carve = [&](size_t bytes) { void* p = w8 + off; off = alignup(off + bytes); return p; };

    int*   row_ptr = (int*)carve((size_t)(N0 + 1) * 4);
    int*   poscnt  = (int*)carve((size_t)N0 * 4);
    int*   part    = (int*)carve(128 * 4);
    int*   col_s   = (int*)carve((size_t)E * 4 + 64);
    float* val_s   = (float*)carve((size_t)E * 4 + 64);
    float* zbuf    = (float*)carve((size_t)B * Z * 4);
    constexpr size_t BIG = (size_t)B * N0 * C;            // 12.8M floats
    float* A1 = (float*)carve(BIG * 4);
    float* A2 = (float*)carve(BIG * 4);
    float* A3 = (float*)carve(BIG * 4);
    (void)ws_size; (void)n_in; (void)in_sizes; (void)out_size;

    // aliases:
    float* T1 = A1 + 0 * BN4;   // padded encoder T buffers (32 MB in A1)
    float* T2 = A1 + 1 * BN4;
    float* T3 = A1 + 2 * BN4;
    float* T4 = A1 + 3 * BN4;
    float* T5 = A1 + 4 * BN4;
    float* HENC = A2;
    float* S0   = A3;
    float* PART = A2;           // enclin partials (12.8 MB), HENC dead by then
    float* P2   = A3 + (size_t)8 * 1024 * 1024;  // 100 KB at +32MB in A3
    float* S1   = A1;           // declin out [B,M]
    float* HUP  = A2;
    float* ACC  = A3;
    float* G    = A1;           // 6 x BN4 (38.4 MB) after dec0
    float* B4   = A2 + 0 * BN4; // Clenshaw b buffers
    float* B3   = A2 + 1 * BN4;
    float* B2   = A2 + 2 * BN4;
    float* B1   = A2 + 3 * BN4;

    const int* dcol = down_idx + DOWN_NNZ;
    const int* ucol = up_idx + UP_NNZ;

    dim3 blk(256);
    dim3 gE((E + 255) / 256);
    dim3 gN0t((N0 + 255) / 256);
    dim3 g3p(((N0 + 255) / 256) * 4);     // 784: prop3g batch-pair, pair = bid & 3
    dim3 gN8(N0 / 8);                     // 6250, exact
    dim3 gNB(N0 / 8, B);
    dim3 gF(N0);                          // 50000: pool3_init, b = id & 7
    dim3 gP4(((N1 + 7) / 8) * 8);         // 12504, b = id & 7

    // ---- CSR build over dst ----
    hipMemsetAsync(poscnt, 0, (size_t)N0 * 4, stream);
    k_hist<<<gE, blk, 0, stream>>>(ei + E, poscnt);
    int nchunks = (N0 + 511) / 512;
    k_scan_chunk<<<nchunks, 512, 0, stream>>>(poscnt, row_ptr, part);
    k_scan_part<<<1, 1, 0, stream>>>(part, nchunks);
    k_scan_add<<<gN0t, blk, 0, stream>>>(part, row_ptr, poscnt);
    k_scatter<<<gE, blk, 0, stream>>>(ei, A_norm, poscnt, col_s, val_s);

    // ---- encoder cheb (Cin=3), padded T buffers ----
    k_prop3g<3,3,4,false,false,false><<<g3p, blk, 0, stream>>>(row_ptr, col_s, val_s, x,  nullptr, nullptr, T1);
    k_prop3g<4,3,4,false,true, true ><<<g3p, blk, 0, stream>>>(row_ptr, col_s, val_s, T1, nullptr, x,  T2);
    k_prop3g<4,4,4,false,true, true ><<<g3p, blk, 0, stream>>>(row_ptr, col_s, val_s, T2, nullptr, T1, T3);
    k_prop3g<4,4,4,false,true, true ><<<g3p, blk, 0, stream>>>(row_ptr, col_s, val_s, T3, nullptr, T2, T4);
    k_prop3g<4,4,4,false,true, true ><<<g3p, blk, 0, stream>>>(row_ptr, col_s, val_s, T4, nullptr, T3, T5);
    k_enc_combine<<<gNB, blk, 0, stream>>>(x, T1, T2, T3, T4, T5, W_enc0, b_enc0, HENC);

    // ---- down pool ----
    k_pool4<<<gP4, blk, 0, stream>>>(dcol, down_val, HENC, S0);

    // ---- enc linear (split-K, parallel tree reduce) ----
    k_enclin1<<<3125, blk, 0, stream>>>(S0, enc_lin_W, PART);
    dim3 g2a(4, 25);
    k_enclin2a<<<g2a, blk, 0, stream>>>(PART, P2);
    k_enclin2b<<<4, blk, 0, stream>>>(P2, enc_lin_b, zbuf);

    // ---- dec linear ----
    k_declin<<<(M + 255) / 256, blk, 0, stream>>>(zbuf, dec_lin_W, dec_lin_b, S1);

    // ---- up pool fused with dec0 k=0 conv ----
    k_pool3_init<<<gF, blk, 0, stream>>>(ucol, up_val, S1, W_dec0, b_dec0, HUP, ACC);

    // ---- dec0 cheb (32->32), batch-vectored; rotate A2<->A1, ACC=A3 ----
    k_prop_fused32<false, true ><<<gN8, blk, 0, stream>>>(row_ptr, col_s, val_s, A2, nullptr, A1, W_dec0 + 1 * C * C, ACC);
    k_prop_fused32<true,  true ><<<gN8, blk, 0, stream>>>(row_ptr, col_s, val_s, A1, A2, A2, W_dec0 + 2 * C * C, ACC);
    k_prop_fused32<true,  true ><<<gN8, blk, 0, stream>>>(row_ptr, col_s, val_s, A2, A1, A1, W_dec0 + 3 * C * C, ACC);
    k_prop_fused32<true,  true ><<<gN8, blk, 0, stream>>>(row_ptr, col_s, val_s, A1, A2, A2, W_dec0 + 4 * C * C, ACC);
    k_prop_fused32<true,  false><<<gN8, blk, 0, stream>>>(row_ptr, col_s, val_s, A2, A1, nullptr, W_dec0 + 5 * C * C, ACC);

    // ---- dec1 via Clenshaw in 3-channel space ----
    k_proj<<<gN8, blk, 0, stream>>>(ACC, W_dec1, G);
    float* G0 = G + 0 * BN4; float* G1 = G + 1 * BN4; float* G2 = G + 2 * BN4;
    float* G3c = G + 3 * BN4; float* G4 = G + 4 * BN4; float* G5 = G + 5 * BN4;
    // b5 = G5; b4 = G4 + 2L b5; b3 = G3 + 2L b4 - b5; b2..; b1..
    k_prop3g<4,4,4,true,false,true ><<<g3p, blk, 0, stream>>>(row_ptr, col_s, val_s, G5, G4, nullptr, B4);
    k_prop3g<4,4,4,true,true, true ><<<g3p, blk, 0, stream>>>(row_ptr, col_s, val_s, B4, G3c, G5, B3);
    k_prop3g<4,4,4,true,true, true ><<<g3p, blk, 0, stream>>>(row_ptr, col_s, val_s, B3, G2, B4, B2);
    k_prop3g<4,4,4,true,true, true ><<<g3p, blk, 0, stream>>>(row_ptr, col_s, val_s, B2, G1, B3, B1);
    // out = G0 + L b1 - b2   (scale 1)
    k_prop3g<4,4,3,true,true, false><<<g3p, blk, 0, stream>>>(row_ptr, col_s, val_s, B1, G0, B2, OUT);
}